// Round 1
// baseline (1665.985 us; speedup 1.0000x reference)
//
#include <hip/hip_runtime.h>

// Fused LSTM + MLP head, fp32 baseline at the fp32-vector roofline.
// B=8192 rows, T=30 steps. 256 blocks x 256 threads, 32 rows/block.
// Each block runs the full 30-step recurrence for its rows:
//   - c state in registers (per-thread, 8 rows x 2 cols)
//   - h / mlp activations in LDS (padded stride 132 for aligned float4 reads)
//   - Wh / W1 / W2 streamed from L2 through a 2x32KB LDS double buffer with
//     register-side prefetch (global->regs, compute, regs->LDS, barrier)
//   - Wi, Wout resident in LDS; biases in registers.

#define T_STEPS 30
#define WARM_N  24
#define HDIM    128
#define FINV    8
#define NGATE   512
#define MLPN    128
#define BR      32          // rows per block
#define KC      16          // k-chunk rows for Wh staging
#define NTHR    256
#define ROWPAD  132         // padded row stride (floats) for h_s/o1_s/o2_s

struct FeatPtrs { const float* f[7]; };

__device__ __forceinline__ float sigmf(float x){ return 1.0f/(1.0f + __expf(-x)); }
__device__ __forceinline__ float tanhfast(float x){ return 1.0f - 2.0f/(__expf(2.0f*x) + 1.0f); }

// 8 float4 per thread = 8192 floats = one staging chunk (KC*NGATE or 64*MLPN)
struct Stage8 {
  float4 v[8];
  __device__ __forceinline__ void load(const float* __restrict__ src, int t){
    const float4* s = (const float4*)src;
#pragma unroll
    for (int i=0;i<8;i++) v[i] = s[t + i*NTHR];
  }
  __device__ __forceinline__ void store(float* dst, int t){
    float4* d = (float4*)dst;
#pragma unroll
    for (int i=0;i<8;i++) d[t + i*NTHR] = v[i];
  }
};

// C[8 rows][2 cols] += A[rows][k] * W[k][2 cols], K=64 chunk, W cols = 128
__device__ __forceinline__ void mlp_chunk(const float* __restrict__ wb,
                                          const float (*A)[ROWPAD],
                                          int tr8, int tc, int kbase,
                                          float m[8][2])
{
#pragma unroll 2
  for (int k4=0; k4<16; ++k4){
    float4 a4[8];
#pragma unroll
    for (int i=0;i<8;i++) a4[i] = *(const float4*)&A[tr8+i][kbase + k4*4];
#pragma unroll
    for (int kk=0; kk<4; ++kk){
      const float* wr = wb + (k4*4+kk)*MLPN + 2*tc;
      float w0 = wr[0], w1 = wr[1];
#pragma unroll
      for (int i=0;i<8;i++){
        float av = ((const float*)&a4[i])[kk];
        m[i][0] = fmaf(av, w0, m[i][0]);
        m[i][1] = fmaf(av, w1, m[i][1]);
      }
    }
  }
}

__global__ __launch_bounds__(NTHR, 1)
void fused_lstm_mlp(FeatPtrs fp, const float* __restrict__ irr,
                    const float* __restrict__ Wi, const float* __restrict__ Wh,
                    const float* __restrict__ bz, const float* __restrict__ W1,
                    const float* __restrict__ b1, const float* __restrict__ W2,
                    const float* __restrict__ b2, const float* __restrict__ Wout,
                    const float* __restrict__ bout, float* __restrict__ out)
{
  __shared__ __align__(16) float h_s [BR][ROWPAD];
  __shared__ __align__(16) float o1_s[BR][ROWPAD];
  __shared__ __align__(16) float o2_s[BR][ROWPAD];
  __shared__ __align__(16) float wbuf[2][KC*NGATE];   // 2 x 32KB
  __shared__ __align__(16) float WiS [FINV*NGATE];    // 16KB resident
  __shared__ __align__(16) float WoutS[MLPN];
  __shared__ float inpS[BR][FINV];
  __shared__ float pS[BR];

  const int t   = threadIdx.x;
  const int tc  = t & 63;        // 64 column-threads -> cols {2tc, 2tc+1}
  const int tr8 = (t >> 6) * 8;  // 4 row-groups of 8 rows
  const int r0  = blockIdx.x * BR;

  // ---- one-time init ----
  {
    const float4* Wi4 = (const float4*)Wi; float4* WiS4 = (float4*)WiS;
#pragma unroll
    for (int i=0;i<4;i++) WiS4[t + i*NTHR] = Wi4[t + i*NTHR];   // 4096 floats
    if (t < MLPN) WoutS[t] = Wout[t];
    for (int i=t; i<BR*ROWPAD; i+=NTHR) (&h_s[0][0])[i] = 0.0f; // h0 = 0
  }
  float bb[2][4], b1v[2], b2v[2];
#pragma unroll
  for (int g=0; g<4; ++g){ bb[0][g] = bz[g*HDIM + 2*tc]; bb[1][g] = bz[g*HDIM + 2*tc + 1]; }
  b1v[0]=b1[2*tc]; b1v[1]=b1[2*tc+1];
  b2v[0]=b2[2*tc]; b2v[1]=b2[2*tc+1];
  const float bout0 = bout[0];
  float creg[8][2];
#pragma unroll
  for (int i=0;i<8;i++){ creg[i][0]=0.0f; creg[i][1]=0.0f; }
  __syncthreads();

  Stage8 st;
  for (int step=0; step<T_STEPS; ++step){
    // ---- gather this step's 8 input features per row ----
    {
      int r = t & 31, j = t >> 5;
      float v;
      if (j < 7)      v = fp.f[j][(r0+r)*T_STEPS + step];
      else if (step < WARM_N) v = irr[(r0+r)*WARM_N + step];
      else            v = pS[r];                    // autoregressive feedback
      inpS[r][j] = v;
    }
    st.load(Wh, t);                                 // prefetch Wh chunk 0
    __syncthreads();

    // ---- z = b + inp@Wi (Wi resident in LDS) ----
    float acc[8][2][4];
#pragma unroll
    for (int i=0;i<8;i++)
#pragma unroll
      for (int c=0;c<2;c++)
#pragma unroll
        for (int g=0;g<4;g++) acc[i][c][g] = bb[c][g];
#pragma unroll
    for (int j=0;j<FINV;j++){
      float a[8];
#pragma unroll
      for (int i=0;i<8;i++) a[i] = inpS[tr8+i][j];
      const float* wr = &WiS[j*NGATE + 2*tc];
#pragma unroll
      for (int g=0;g<4;g++){
        float w0 = wr[g*HDIM], w1 = wr[g*HDIM+1];
#pragma unroll
        for (int i=0;i<8;i++){
          acc[i][0][g] = fmaf(a[i], w0, acc[i][0][g]);
          acc[i][1][g] = fmaf(a[i], w1, acc[i][1][g]);
        }
      }
    }
    st.store(wbuf[0], t);
    __syncthreads();

    // ---- z += h@Wh : 8 chunks of 16 k, double buffered ----
    for (int ch=0; ch<8; ++ch){
      if (ch < 7) st.load(Wh + (ch+1)*KC*NGATE, t);
      const float* wb = wbuf[ch & 1];
#pragma unroll 2
      for (int k4=0; k4<KC/4; ++k4){
        float4 a4[8];
#pragma unroll
        for (int i=0;i<8;i++) a4[i] = *(const float4*)&h_s[tr8+i][ch*KC + k4*4];
#pragma unroll
        for (int kk=0; kk<4; ++kk){
          const float* wr = wb + (k4*4+kk)*NGATE + 2*tc;
#pragma unroll
          for (int g=0; g<4; ++g){
            float w0 = wr[g*HDIM], w1 = wr[g*HDIM+1];
#pragma unroll
            for (int i=0;i<8;i++){
              float av = ((const float*)&a4[i])[kk];
              acc[i][0][g] = fmaf(av, w0, acc[i][0][g]);
              acc[i][1][g] = fmaf(av, w1, acc[i][1][g]);
            }
          }
        }
      }
      if (ch < 7) st.store(wbuf[(ch+1)&1], t);
      __syncthreads();
    }

    // ---- gate activations, update c (regs) and h (LDS) ----
    st.load(W1, t);                                 // prefetch W1 chunk 0
#pragma unroll
    for (int i=0;i<8;i++){
      float2 hv;
#pragma unroll
      for (int c=0;c<2;c++){
        float zi = acc[i][c][0], zf = acc[i][c][1];
        float zg = acc[i][c][2], zo = acc[i][c][3];
        float c2 = sigmf(zf)*creg[i][c] + sigmf(zi)*tanhfast(zg);
        creg[i][c] = c2;
        float h2 = sigmf(zo)*tanhfast(c2);
        if (c==0) hv.x = h2; else hv.y = h2;
      }
      *(float2*)&h_s[tr8+i][2*tc] = hv;
    }
    st.store(wbuf[0], t);
    __syncthreads();

    // ---- MLP layer 1: o1 = relu(h@W1 + b1) ----
    float m[8][2];
#pragma unroll
    for (int i=0;i<8;i++){ m[i][0]=b1v[0]; m[i][1]=b1v[1]; }
    st.load(W1 + 64*MLPN, t);                       // W1 chunk 1
    mlp_chunk(&wbuf[0][0], h_s, tr8, tc, 0, m);
    st.store(wbuf[1], t);
    __syncthreads();
    st.load(W2, t);                                 // W2 chunk 0
    mlp_chunk(&wbuf[1][0], h_s, tr8, tc, 64, m);
    st.store(wbuf[0], t);
#pragma unroll
    for (int i=0;i<8;i++){
      float2 v; v.x = fmaxf(m[i][0],0.0f); v.y = fmaxf(m[i][1],0.0f);
      *(float2*)&o1_s[tr8+i][2*tc] = v;
    }
    __syncthreads();

    // ---- MLP layer 2: o2 = relu(o1@W2 + b2) ----
    float m2[8][2];
#pragma unroll
    for (int i=0;i<8;i++){ m2[i][0]=b2v[0]; m2[i][1]=b2v[1]; }
    st.load(W2 + 64*MLPN, t);                       // W2 chunk 1
    mlp_chunk(&wbuf[0][0], o1_s, tr8, tc, 0, m2);
    st.store(wbuf[1], t);
    __syncthreads();
    mlp_chunk(&wbuf[1][0], o1_s, tr8, tc, 64, m2);
#pragma unroll
    for (int i=0;i<8;i++){
      float2 v; v.x = fmaxf(m2[i][0],0.0f); v.y = fmaxf(m2[i][1],0.0f);
      *(float2*)&o2_s[tr8+i][2*tc] = v;
    }
    __syncthreads();

    // ---- output head: p = o2 . Wout + bout ; store pred; keep for feedback
    {
      int r = t >> 3, j = t & 7;                    // 8 threads per row
      const float4* row = (const float4*)&o2_s[r][0];
      float s = 0.0f;
#pragma unroll
      for (int q=0; q<4; ++q){
        float4 v = row[j*4 + q];
        float4 w = *(const float4*)&WoutS[j*16 + q*4];
        s += v.x*w.x + v.y*w.y + v.z*w.z + v.w*w.w;
      }
      s += __shfl_down(s, 4, 8);
      s += __shfl_down(s, 2, 8);
      s += __shfl_down(s, 1, 8);
      if (j == 0){
        float p = s + bout0;
        out[(r0+r)*T_STEPS + step] = p;
        pS[r] = p;
      }
    }
    __syncthreads();   // pS visible before next step's input gather
  }
}

extern "C" void kernel_launch(void* const* d_in, const int* in_sizes, int n_in,
                              void* d_out, int out_size, void* d_ws, size_t ws_size,
                              hipStream_t stream)
{
  (void)in_sizes; (void)n_in; (void)d_ws; (void)ws_size; (void)out_size;
  // input order: 0..7 weather (UNUSED by reference), 8..14 time features,
  // 15 irradiance_in, 16 Wi, 17 Wh, 18 b, 19 W1, 20 b1, 21 W2, 22 b2,
  // 23 Wout, 24 bout
  FeatPtrs fp;
  for (int j=0;j<7;j++) fp.f[j] = (const float*)d_in[8+j];
  const float* irr  = (const float*)d_in[15];
  const float* Wi   = (const float*)d_in[16];
  const float* Wh   = (const float*)d_in[17];
  const float* bz   = (const float*)d_in[18];
  const float* W1   = (const float*)d_in[19];
  const float* b1   = (const float*)d_in[20];
  const float* W2   = (const float*)d_in[21];
  const float* b2   = (const float*)d_in[22];
  const float* Wout = (const float*)d_in[23];
  const float* bout = (const float*)d_in[24];
  float* out = (float*)d_out;

  fused_lstm_mlp<<<dim3(256), dim3(NTHR), 0, stream>>>(
      fp, irr, Wi, Wh, bz, W1, b1, W2, b2, Wout, bout, out);
}

// Round 2
// 246.918 us; speedup vs baseline: 6.7471x; 6.7471x over previous
//
#include <hip/hip_runtime.h>

// Fused LSTM(H=128) + 3-layer MLP head, bf16 MFMA (32x32x16), fp32 state.
// B=8192 rows, T=30 steps. 256 blocks x 256 threads (4 waves), 32 rows/block.
// - Weights live in VGPRs as pre-packed bf16 B-fragments (pack kernel -> d_ws).
// - Wave w owns output cols [32w,32w+32) of every GEMM; z-GEMM N-tiles at
//   g*128+32w for g=0..3 => (i,f,g,o) quadruple + c-state are in-lane.
// - Activations (x,h) use split bf16 hi+lo (error ~2^-17); o1 single bf16.
// - fp32: accumulators, c, gate nonlinearities, o2, output head, feedback p.
// - LDS A-panels: [kstep][32 rows][24 shorts] (16 data + 8 pad, 48B rows).

#define T_STEPS 30
#define WARM_N  24

typedef __attribute__((ext_vector_type(8)))  short short8;   // 8 bf16 = 4 VGPRs
typedef __attribute__((ext_vector_type(16))) float float16;  // MFMA 32x32 C/D

struct FeatPtrs { const float* f[7]; };

__device__ __forceinline__ short f2bf(float f){
  unsigned u = __float_as_uint(f);
  unsigned r = (u + 0x7fffu + ((u >> 16) & 1u)) >> 16;   // round-nearest-even
  return (short)r;
}
__device__ __forceinline__ float bf2f(short h){
  return __uint_as_float(((unsigned)(unsigned short)h) << 16);
}

#if __has_builtin(__builtin_amdgcn_rcpf)
#define RCP(x) __builtin_amdgcn_rcpf(x)
#else
#define RCP(x) (1.0f/(x))
#endif

__device__ __forceinline__ float sigm(float x){ return RCP(1.0f + __expf(-x)); }
__device__ __forceinline__ float tanh_(float x){ return 1.0f - 2.0f*RCP(1.0f + __expf(2.0f*x)); }

// ---------------- weight pack kernel ----------------
// ws layout (bf16), frag = 64 lanes x 8 bf16 = 512 elems:
//  frags 0..143 : z-weights [hq 0..3][g 0..3][kst 0..8]; kst0 = Wi (k 0..7 real,
//                 8..15 zero-pad), kst 1..8 = Wh k-chunks of 16.
//  frags 144..175: W1 [nt 0..3][kst 0..7];  176..207: W2 same.
// frag element (lane,j): B[k = kst*16 + (lane>>5)*8 + j][n = colbase + (lane&31)]
__global__ void pack_weights(const float* __restrict__ Wi, const float* __restrict__ Wh,
                             const float* __restrict__ W1, const float* __restrict__ W2,
                             short* __restrict__ ws)
{
  int idx = blockIdx.x * 256 + threadIdx.x;
  if (idx >= 208 * 512) return;
  int f    = idx >> 9;
  int r    = idx & 511;
  int lane = r >> 3, j = r & 7;
  int kl   = ((lane >> 5) << 3) + j;     // k within 16
  int n32  = lane & 31;
  float v;
  if (f < 144){
    int hq = f / 36, rem = f % 36, g = rem / 9, kst = rem % 9;
    int col = g * 128 + hq * 32 + n32;
    if (kst == 0) v = (kl < 8) ? Wi[kl * 512 + col] : 0.0f;
    else          v = Wh[((kst - 1) * 16 + kl) * 512 + col];
  } else {
    int f2 = f - 144;                    // 0..63
    const float* W = (f2 < 32) ? W1 : W2;
    int f3 = f2 & 31;
    int nt = f3 >> 3, kst = f3 & 7;
    v = W[(kst * 16 + kl) * 128 + nt * 32 + n32];
  }
  ws[idx] = f2bf(v);
}

// ---------------- main kernel ----------------
__global__ __launch_bounds__(256, 1)
void lstm_mfma(FeatPtrs fp, const float* __restrict__ irr,
               const short* __restrict__ wsb,
               const float* __restrict__ bz, const float* __restrict__ b1,
               const float* __restrict__ b2, const float* __restrict__ Wout,
               const float* __restrict__ bout, float* __restrict__ out)
{
  __shared__ __align__(16) short xh[2][768];        // x hi/lo, 1 panel each
  __shared__ __align__(16) short hp[2][8 * 768];    // h hi/lo, 8 panels
  __shared__ __align__(16) short o1p[8 * 768];      // o1 single, 8 panels
  __shared__ __align__(16) float o2s[32 * 132];     // o2 fp32, padded rows
  __shared__ float WoutS[128];
  __shared__ float pS[32];

  const int t    = threadIdx.x;
  const int l    = t & 63;
  const int w    = t >> 6;
  const int ln31 = l & 31;
  const int half = l >> 5;
  const int r0   = blockIdx.x * 32;

  // weight fragments -> registers (coalesced dwordx4 loads)
  short8 Bz[4][9], B1f[8], B2f[8];
  {
    const short8* f8 = (const short8*)wsb;
#pragma unroll
    for (int g = 0; g < 4; ++g)
#pragma unroll
      for (int ks = 0; ks < 9; ++ks)
        Bz[g][ks] = f8[((w * 4 + g) * 9 + ks) * 64 + l];
#pragma unroll
    for (int ks = 0; ks < 8; ++ks) B1f[ks] = f8[(144 + w * 8 + ks) * 64 + l];
#pragma unroll
    for (int ks = 0; ks < 8; ++ks) B2f[ks] = f8[(176 + w * 8 + ks) * 64 + l];
  }
  float bzv[4];
#pragma unroll
  for (int g = 0; g < 4; ++g) bzv[g] = bz[g * 128 + w * 32 + ln31];
  const float b1v   = b1[w * 32 + ln31];
  const float b2v   = b2[w * 32 + ln31];
  const float bout0 = bout[0];
  if (t < 128) WoutS[t] = Wout[t];

  { // zero x panels (pad cols must stay 0) and h panels (h0 = 0)
    int* p = (int*)&xh[0][0];
    for (int i = t; i < 768;  i += 256) p[i] = 0;
    p = (int*)&hp[0][0];
    for (int i = t; i < 6144; i += 256) p[i] = 0;
  }

  float cst[16];
#pragma unroll
  for (int i = 0; i < 16; ++i) cst[i] = 0.0f;

  const int aoff   = ln31 * 24 + half * 8;              // A-frag read offset (shorts)
  const int hcol   = w * 32 + ln31;                     // this lane's output col
  const int hwbase = (hcol >> 4) * 768 + (hcol & 15);   // activation write base
  __syncthreads();

  for (int step = 0; step < T_STEPS; ++step){
    { // ---- gather 8 input features per row, split hi/lo ----
      int r = t >> 3, j = t & 7;
      float v;
      if (j < 7)               v = fp.f[j][(r0 + r) * T_STEPS + step];
      else if (step < WARM_N)  v = irr[(r0 + r) * WARM_N + step];
      else                     v = pS[r];               // autoregressive feedback
      short hi = f2bf(v);
      xh[0][r * 24 + j] = hi;
      xh[1][r * 24 + j] = f2bf(v - bf2f(hi));
    }
    __syncthreads();

    // ---- z = b + [x_hi+x_lo]@Wi + [h_hi+h_lo]@Wh  (4 gate tiles in-lane) ----
    float16 acc[4];
#pragma unroll
    for (int g = 0; g < 4; ++g)
#pragma unroll
      for (int r = 0; r < 16; ++r) acc[g][r] = bzv[g];
    {
      short8 a0 = *(const short8*)&xh[0][aoff];
      short8 a1 = *(const short8*)&xh[1][aoff];
#pragma unroll
      for (int g = 0; g < 4; ++g){
        acc[g] = __builtin_amdgcn_mfma_f32_32x32x16_bf16(a0, Bz[g][0], acc[g], 0, 0, 0);
        acc[g] = __builtin_amdgcn_mfma_f32_32x32x16_bf16(a1, Bz[g][0], acc[g], 0, 0, 0);
      }
    }
#pragma unroll
    for (int ks = 0; ks < 8; ++ks){
      short8 ah = *(const short8*)&hp[0][ks * 768 + aoff];
      short8 al = *(const short8*)&hp[1][ks * 768 + aoff];
#pragma unroll
      for (int g = 0; g < 4; ++g){
        acc[g] = __builtin_amdgcn_mfma_f32_32x32x16_bf16(ah, Bz[g][1 + ks], acc[g], 0, 0, 0);
        acc[g] = __builtin_amdgcn_mfma_f32_32x32x16_bf16(al, Bz[g][1 + ks], acc[g], 0, 0, 0);
      }
    }
    __syncthreads();   // all panel reads done before h rewrite

    // ---- gates (fp32, in-lane), update c, write h hi/lo panels ----
#pragma unroll
    for (int r = 0; r < 16; ++r){
      float zi = acc[0][r], zf = acc[1][r], zg = acc[2][r], zo = acc[3][r];
      float c2 = sigm(zf) * cst[r] + sigm(zi) * tanh_(zg);
      cst[r] = c2;
      float h2 = sigm(zo) * tanh_(c2);
      int row = (r & 3) + 8 * (r >> 2) + 4 * half;      // verified C/D row map
      short hi = f2bf(h2);
      hp[0][hwbase + row * 24] = hi;
      hp[1][hwbase + row * 24] = f2bf(h2 - bf2f(hi));
    }
    __syncthreads();

    // ---- MLP1: o1 = relu(h@W1 + b1) ----
    float16 m1;
#pragma unroll
    for (int r = 0; r < 16; ++r) m1[r] = b1v;
#pragma unroll
    for (int ks = 0; ks < 8; ++ks){
      short8 ah = *(const short8*)&hp[0][ks * 768 + aoff];
      m1 = __builtin_amdgcn_mfma_f32_32x32x16_bf16(ah, B1f[ks], m1, 0, 0, 0);
      short8 al = *(const short8*)&hp[1][ks * 768 + aoff];
      m1 = __builtin_amdgcn_mfma_f32_32x32x16_bf16(al, B1f[ks], m1, 0, 0, 0);
    }
#pragma unroll
    for (int r = 0; r < 16; ++r){
      int row = (r & 3) + 8 * (r >> 2) + 4 * half;
      o1p[hwbase + row * 24] = f2bf(fmaxf(m1[r], 0.0f));
    }
    __syncthreads();

    // ---- MLP2: o2 = relu(o1@W2 + b2), store fp32 ----
    float16 m2;
#pragma unroll
    for (int r = 0; r < 16; ++r) m2[r] = b2v;
#pragma unroll
    for (int ks = 0; ks < 8; ++ks){
      short8 a = *(const short8*)&o1p[ks * 768 + aoff];
      m2 = __builtin_amdgcn_mfma_f32_32x32x16_bf16(a, B2f[ks], m2, 0, 0, 0);
    }
#pragma unroll
    for (int r = 0; r < 16; ++r){
      int row = (r & 3) + 8 * (r >> 2) + 4 * half;
      o2s[row * 132 + hcol] = fmaxf(m2[r], 0.0f);
    }
    __syncthreads();

    // ---- head: p = o2 . Wout + bout (fp32 exact), 8 threads/row ----
    {
      int r = t >> 3, jj = t & 7;
      const float* orow = &o2s[r * 132 + jj * 16];
      const float* wrow = &WoutS[jj * 16];
      float s = 0.0f;
#pragma unroll
      for (int q = 0; q < 16; ++q) s += orow[q] * wrow[q];
      s += __shfl_down(s, 4, 8);
      s += __shfl_down(s, 2, 8);
      s += __shfl_down(s, 1, 8);
      if (jj == 0){
        float p = s + bout0;
        out[(r0 + r) * T_STEPS + step] = p;
        pS[r] = p;
      }
    }
    __syncthreads();   // pS/panels visible before next step
  }
}

extern "C" void kernel_launch(void* const* d_in, const int* in_sizes, int n_in,
                              void* d_out, int out_size, void* d_ws, size_t ws_size,
                              hipStream_t stream)
{
  (void)in_sizes; (void)n_in; (void)out_size; (void)ws_size;
  // inputs: 0..7 weather (unused), 8..14 time feats, 15 irradiance_in,
  // 16 Wi, 17 Wh, 18 b, 19 W1, 20 b1, 21 W2, 22 b2, 23 Wout, 24 bout
  FeatPtrs fp;
  for (int j = 0; j < 7; ++j) fp.f[j] = (const float*)d_in[8 + j];
  const float* irr  = (const float*)d_in[15];
  const float* Wi   = (const float*)d_in[16];
  const float* Wh   = (const float*)d_in[17];
  const float* bz   = (const float*)d_in[18];
  const float* W1   = (const float*)d_in[19];
  const float* b1   = (const float*)d_in[20];
  const float* W2   = (const float*)d_in[21];
  const float* b2   = (const float*)d_in[22];
  const float* Wout = (const float*)d_in[23];
  const float* bout = (const float*)d_in[24];

  short* ws = (short*)d_ws;                       // 208*512*2 = 208 KB used
  pack_weights<<<dim3(416), dim3(256), 0, stream>>>(Wi, Wh, W1, W2, ws);
  lstm_mfma<<<dim3(256), dim3(256), 0, stream>>>(
      fp, irr, ws, bz, b1, b2, Wout, bout, (float*)d_out);
}